// Round 3
// baseline (593.855 us; speedup 1.0000x reference)
//
#include <hip/hip_runtime.h>
#include <cstdint>
#include <cstddef>

#define B_SZ 4
#define T_SZ 2048
#define NH 16
#define HD 64
#define CD 1024
#define MROWS (B_SZ*T_SZ)
#define NEG_BIG (-1e30f)

typedef __bf16 bf16x8 __attribute__((ext_vector_type(8)));
typedef float f32x4 __attribute__((ext_vector_type(4)));
typedef unsigned short u16;
typedef u16 u16x8 __attribute__((ext_vector_type(8)));

typedef __attribute__((address_space(3))) void* as3p;
typedef const __attribute__((address_space(1))) void* as1p;

__device__ __forceinline__ void glds16(const void* g, void* l) {
  __builtin_amdgcn_global_load_lds((as1p)g, (as3p)l, 16, 0, 0);
}

// ---------------------------------------------------------------------------
// Dtype discriminator. Reads 1024 u32 words of x. For bf16-pair words,
// bits[14:7] is the low bf16's exponent (~always in [100,140] for N(0,1)
// data). For fp32 words, bits[14:7] are mantissa bits (uniform -> ~16% in
// range). flag=1 -> inputs are bf16; flag=0 -> fp32.
// ---------------------------------------------------------------------------
__global__ __launch_bounds__(256) void detect_dtype(const uint32_t* __restrict__ x,
                                                    int* __restrict__ flag) {
  __shared__ int cnt[256];
  const int t = threadIdx.x;
  int c = 0;
  for (int i = 0; i < 4; i++) {
    uint32_t w = x[t * 4 + i];
    uint32_t e = (w >> 7) & 0xFF;
    c += (e >= 100 && e <= 140) ? 1 : 0;
  }
  cnt[t] = c;
  __syncthreads();
  for (int s = 128; s > 0; s >>= 1) {
    if (t < s) cnt[t] += cnt[t + s];
    __syncthreads();
  }
  if (t == 0) flag[0] = (cnt[0] > 700) ? 1 : 0;
}

// ---------------------------------------------------------------------------
// Convert n8*8 elements (fp32 or bf16 per flag) to canonical bf16.
// ---------------------------------------------------------------------------
__global__ __launch_bounds__(256) void conv_in(const void* __restrict__ src,
                                               const int* __restrict__ flag,
                                               __bf16* __restrict__ dst, int n8) {
  int i = blockIdx.x * 256 + threadIdx.x;
  if (i >= n8) return;
  bf16x8 o;
  if (flag[0]) {
    o = ((const bf16x8*)src)[i];
  } else {
    const float4* s = (const float4*)((const float*)src + (size_t)i * 8);
    float4 a = s[0], b = s[1];
    o[0] = (__bf16)a.x; o[1] = (__bf16)a.y; o[2] = (__bf16)a.z; o[3] = (__bf16)a.w;
    o[4] = (__bf16)b.x; o[5] = (__bf16)b.y; o[6] = (__bf16)b.z; o[7] = (__bf16)b.w;
  }
  ((bf16x8*)dst)[i] = o;
}

// ---------------------------------------------------------------------------
// Write canonical bf16 result to d_out in the flagged dtype.
// ---------------------------------------------------------------------------
__global__ __launch_bounds__(256) void writeout(const __bf16* __restrict__ src,
                                                const int* __restrict__ flag,
                                                void* __restrict__ dst, int n8) {
  int i = blockIdx.x * 256 + threadIdx.x;
  if (i >= n8) return;
  bf16x8 v = ((const bf16x8*)src)[i];
  if (flag[0]) {
    ((bf16x8*)dst)[i] = v;
  } else {
    float4* d = (float4*)((float*)dst + (size_t)i * 8);
    float4 a, b;
    a.x = (float)v[0]; a.y = (float)v[1]; a.z = (float)v[2]; a.w = (float)v[3];
    b.x = (float)v[4]; b.y = (float)v[5]; b.z = (float)v[6]; b.w = (float)v[7];
    d[0] = a; d[1] = b;
  }
}

// ---------------------------------------------------------------------------
// Transpose 1024x1024 (fp32 or bf16 per flag) -> canonical bf16 WT[n][k].
// ---------------------------------------------------------------------------
__global__ __launch_bounds__(256) void transpose_conv(const void* __restrict__ W,
                                                      const int* __restrict__ flag,
                                                      __bf16* __restrict__ WT) {
  __shared__ __align__(16) __bf16 tile[64 * 72];
  const int t = threadIdx.x;
  const int r0 = blockIdx.y * 64, c0 = blockIdx.x * 64;
  const int rr = t >> 3, c8 = (t & 7) * 8;
  const int isbf = flag[0];
  for (int p = 0; p < 2; p++) {
    int r = p * 32 + rr;
    bf16x8 v;
    if (isbf) {
      v = *(const bf16x8*)((const __bf16*)W + (size_t)(r0 + r) * CD + c0 + c8);
    } else {
      const float4* s = (const float4*)((const float*)W + (size_t)(r0 + r) * CD + c0 + c8);
      float4 a = s[0], b = s[1];
      v[0] = (__bf16)a.x; v[1] = (__bf16)a.y; v[2] = (__bf16)a.z; v[3] = (__bf16)a.w;
      v[4] = (__bf16)b.x; v[5] = (__bf16)b.y; v[6] = (__bf16)b.z; v[7] = (__bf16)b.w;
    }
    *(bf16x8*)(tile + r * 72 + c8) = v;
  }
  __syncthreads();
  for (int p = 0; p < 2; p++) {
    int cc = p * 32 + rr;
    bf16x8 o;
    for (int j = 0; j < 8; j++) o[j] = tile[(c8 + j) * 72 + cc];
    *(bf16x8*)(WT + (size_t)(c0 + cc) * CD + r0 + c8) = o;
  }
}

// ---------------------------------------------------------------------------
// C[M,N] = A[M,K] @ BT[N,K]^T + bias, canonical bf16 in/out, fp32 accum.
// mode 0: scale 1/8, write [B,H,T,64]   (Q)
// mode 1: write [B,H,T,64]              (K, V)
// mode 2: write flat [M,N]              (out-proj, to bf16 scratch)
// ---------------------------------------------------------------------------
__global__ __launch_bounds__(256) void gemm_bt(
    const __bf16* __restrict__ A, const __bf16* __restrict__ BT,
    const __bf16* __restrict__ bias, __bf16* __restrict__ Cout,
    int Kdim, int Ndim, int mode) {
  __shared__ __align__(16) __bf16 As[128 * 64];
  __shared__ __align__(16) __bf16 Bs[128 * 64];
  const int tid = threadIdx.x;
  const int w = tid >> 6, lane = tid & 63;
  const int l15 = lane & 15, quad = lane >> 4;
  const int wm = w & 1, wn = w >> 1;
  const int bm = blockIdx.y, bn = blockIdx.x;

  f32x4 acc[4][4];
  for (int i = 0; i < 4; i++)
    for (int j = 0; j < 4; j++) acc[i][j] = (f32x4)0.f;

  const int srow = lane >> 3, scol = (lane & 7) * 8;
  const __bf16* Abase = A + (size_t)(bm * 128) * Kdim;
  const __bf16* Bbase = BT + (size_t)(bn * 128) * Kdim;

  for (int k0 = 0; k0 < Kdim; k0 += 64) {
    __syncthreads();
    for (int p = 0; p < 4; p++) {
      int seg = p * 4 + w;
      int row = seg * 8 + srow;
      glds16(Abase + (size_t)row * Kdim + k0 + scol, (char*)As + seg * 1024);
      glds16(Bbase + (size_t)row * Kdim + k0 + scol, (char*)Bs + seg * 1024);
    }
    __syncthreads();
    for (int kc = 0; kc < 2; kc++) {
      const int koff = kc * 32 + quad * 8;
      bf16x8 af[4], bfr[4];
      for (int mt = 0; mt < 4; mt++)
        af[mt] = *(const bf16x8*)(As + (wm * 64 + mt * 16 + l15) * 64 + koff);
      for (int nt = 0; nt < 4; nt++)
        bfr[nt] = *(const bf16x8*)(Bs + (wn * 64 + nt * 16 + l15) * 64 + koff);
      for (int mt = 0; mt < 4; mt++)
        for (int nt = 0; nt < 4; nt++)
          acc[mt][nt] = __builtin_amdgcn_mfma_f32_16x16x32_bf16(
              af[mt], bfr[nt], acc[mt][nt], 0, 0, 0);
    }
  }

  for (int nt = 0; nt < 4; nt++) {
    int col = bn * 128 + wn * 64 + nt * 16 + l15;
    float bv = (float)bias[col];
    for (int mt = 0; mt < 4; mt++) {
      for (int r = 0; r < 4; r++) {
        int row = bm * 128 + wm * 64 + mt * 16 + quad * 4 + r;
        float v = acc[mt][nt][r] + bv;
        size_t idx;
        if (mode == 2) {
          idx = (size_t)row * Ndim + col;
        } else {
          if (mode == 0) v *= 0.125f;
          idx = (((size_t)(row >> 11) * NH + (col >> 6)) * T_SZ + (row & 2047)) * HD + (col & 63);
        }
        Cout[idx] = (__bf16)v;
      }
    }
  }
}

// ---------------------------------------------------------------------------
// Flash attention, causal. Q pre-scaled by 1/8. Q/K/V: [B*H, T, 64] bf16.
// ---------------------------------------------------------------------------
__global__ __launch_bounds__(256) void attn(
    const __bf16* __restrict__ Q, const __bf16* __restrict__ K,
    const __bf16* __restrict__ V, __bf16* __restrict__ Y) {
  __shared__ __align__(16) __bf16 Ks[64 * 72];
  __shared__ __align__(16) __bf16 Vt[64 * 72];   // [d][key]
  __shared__ __align__(16) __bf16 Ps[4][16 * 72];

  const int tid = threadIdx.x, w = tid >> 6, lane = tid & 63;
  const int l15 = lane & 15, quad = lane >> 4;
  const int bh = blockIdx.y;
  const int q0 = blockIdx.x * 64;
  const int qrow = q0 + w * 16 + l15;

  const __bf16* Qbh = Q + (size_t)bh * T_SZ * HD;
  const __bf16* Kbh = K + (size_t)bh * T_SZ * HD;
  const __bf16* Vbh = V + (size_t)bh * T_SZ * HD;

  bf16x8 aq[2];
  aq[0] = *(const bf16x8*)(Qbh + qrow * HD + quad * 8);
  aq[1] = *(const bf16x8*)(Qbh + qrow * HD + 32 + quad * 8);

  f32x4 acco[4];
  for (int dt = 0; dt < 4; dt++) acco[dt] = (f32x4)0.f;
  float m_r[4], l_r[4];
  for (int r = 0; r < 4; r++) { m_r[r] = NEG_BIG; l_r[r] = 0.f; }

  const int srow = tid >> 3, scol = (tid & 7) * 8;

  for (int kv0 = 0; kv0 <= q0; kv0 += 64) {
    __syncthreads();
    for (int p = 0; p < 2; p++) {
      int r = p * 32 + srow;
      bf16x8 kv = *(const bf16x8*)(Kbh + (size_t)(kv0 + r) * HD + scol);
      *(bf16x8*)(Ks + r * 72 + scol) = kv;
      bf16x8 vv = *(const bf16x8*)(Vbh + (size_t)(kv0 + r) * HD + scol);
      for (int j = 0; j < 8; j++) Vt[(scol + j) * 72 + r] = vv[j];
    }
    __syncthreads();

    f32x4 accs[4];
    for (int nt = 0; nt < 4; nt++) accs[nt] = (f32x4)0.f;
    for (int kc = 0; kc < 2; kc++) {
      const int koff = kc * 32 + quad * 8;
      for (int nt = 0; nt < 4; nt++) {
        bf16x8 bk = *(const bf16x8*)(Ks + (nt * 16 + l15) * 72 + koff);
        accs[nt] = __builtin_amdgcn_mfma_f32_16x16x32_bf16(aq[kc], bk, accs[nt], 0, 0, 0);
      }
    }

    float sv[4][4];
    float mloc[4];
    for (int r = 0; r < 4; r++) mloc[r] = NEG_BIG;
    for (int nt = 0; nt < 4; nt++) {
      int kg = kv0 + nt * 16 + l15;
      for (int r = 0; r < 4; r++) {
        int qg = q0 + w * 16 + quad * 4 + r;
        float s = accs[nt][r];
        if (kg > qg) s = NEG_BIG;
        sv[nt][r] = s;
        mloc[r] = fmaxf(mloc[r], s);
      }
    }
    for (int off = 1; off < 16; off <<= 1)
      for (int r = 0; r < 4; r++)
        mloc[r] = fmaxf(mloc[r], __shfl_xor(mloc[r], off));
    float alpha[4], rs[4];
    for (int r = 0; r < 4; r++) {
      float mnew = fmaxf(m_r[r], mloc[r]);
      alpha[r] = __expf(m_r[r] - mnew);
      m_r[r] = mnew;
      rs[r] = 0.f;
    }
    for (int nt = 0; nt < 4; nt++)
      for (int r = 0; r < 4; r++) {
        float p = __expf(sv[nt][r] - m_r[r]);
        rs[r] += p;
        Ps[w][(quad * 4 + r) * 72 + nt * 16 + l15] = (__bf16)p;
      }
    for (int off = 1; off < 16; off <<= 1)
      for (int r = 0; r < 4; r++) rs[r] += __shfl_xor(rs[r], off);
    for (int r = 0; r < 4; r++) l_r[r] = l_r[r] * alpha[r] + rs[r];
    for (int dt = 0; dt < 4; dt++)
      for (int r = 0; r < 4; r++) acco[dt][r] *= alpha[r];

    __syncthreads();

    for (int kc = 0; kc < 2; kc++) {
      bf16x8 ap = *(const bf16x8*)(Ps[w] + l15 * 72 + kc * 32 + quad * 8);
      for (int dt = 0; dt < 4; dt++) {
        bf16x8 bv = *(const bf16x8*)(Vt + (dt * 16 + l15) * 72 + kc * 32 + quad * 8);
        acco[dt] = __builtin_amdgcn_mfma_f32_16x16x32_bf16(ap, bv, acco[dt], 0, 0, 0);
      }
    }
  }

  const int b = bh >> 4, h = bh & 15;
  for (int dt = 0; dt < 4; dt++)
    for (int r = 0; r < 4; r++) {
      int qg = q0 + w * 16 + quad * 4 + r;
      float ov = acco[dt][r] / l_r[r];
      Y[((size_t)(b * T_SZ + qg)) * CD + h * HD + dt * 16 + l15] = (__bf16)ov;
    }
}

// ---------------------------------------------------------------------------
extern "C" void kernel_launch(void* const* d_in, const int* in_sizes, int n_in,
                              void* d_out, int out_size, void* d_ws, size_t ws_size,
                              hipStream_t stream) {
  (void)in_sizes; (void)n_in; (void)out_size; (void)ws_size;
  const void* x  = d_in[0];
  // d_in[1] = mask (int32 tril) — causality applied analytically
  const void* Wq = d_in[2];
  const void* bq = d_in[3];
  const void* Wk = d_in[4];
  const void* bk = d_in[5];
  const void* Wv = d_in[6];
  const void* bv = d_in[7];
  const void* Wo = d_in[8];
  const void* bo = d_in[9];

  char* ws = (char*)d_ws;
  const size_t MB = 1024 * 1024;
  __bf16* xc   = (__bf16*)(ws + 0 * MB);            // [8192,1024]; later Yb
  __bf16* WqT  = (__bf16*)(ws + 16 * MB);
  __bf16* WkT  = (__bf16*)(ws + 18 * MB);
  __bf16* WvT  = (__bf16*)(ws + 20 * MB);
  __bf16* WoT  = (__bf16*)(ws + 22 * MB);
  __bf16* bqc  = (__bf16*)(ws + 24 * MB);
  __bf16* bkc  = (__bf16*)(ws + 24 * MB + 8192);
  __bf16* bvc  = (__bf16*)(ws + 24 * MB + 16384);
  __bf16* boc  = (__bf16*)(ws + 24 * MB + 24576);
  int*    flag = (int*)   (ws + 24 * MB + 65536);
  __bf16* Qb   = (__bf16*)(ws + 25 * MB);           // [B*H,T,64] pre-scaled
  __bf16* Kb   = (__bf16*)(ws + 41 * MB);           // later: bf16 final out
  __bf16* Vb   = (__bf16*)(ws + 57 * MB);
  __bf16* Yb   = xc;                                // attn output (xc dead)
  __bf16* Outc = Kb;                                // out-proj bf16 (Kb dead)

  dim3 tb(256);
  detect_dtype<<<1, tb, 0, stream>>>((const uint32_t*)x, flag);

  conv_in<<<4096, tb, 0, stream>>>(x, flag, xc, MROWS * CD / 8);
  conv_in<<<1, tb, 0, stream>>>(bq, flag, bqc, CD / 8);
  conv_in<<<1, tb, 0, stream>>>(bk, flag, bkc, CD / 8);
  conv_in<<<1, tb, 0, stream>>>(bv, flag, bvc, CD / 8);
  conv_in<<<1, tb, 0, stream>>>(bo, flag, boc, CD / 8);

  dim3 tg(16, 16);
  transpose_conv<<<tg, tb, 0, stream>>>(Wq, flag, WqT);
  transpose_conv<<<tg, tb, 0, stream>>>(Wk, flag, WkT);
  transpose_conv<<<tg, tb, 0, stream>>>(Wv, flag, WvT);
  transpose_conv<<<tg, tb, 0, stream>>>(Wo, flag, WoT);

  dim3 gg(CD / 128, MROWS / 128);
  gemm_bt<<<gg, tb, 0, stream>>>(xc, WqT, bqc, Qb, CD, CD, 0);
  gemm_bt<<<gg, tb, 0, stream>>>(xc, WkT, bkc, Kb, CD, CD, 1);
  gemm_bt<<<gg, tb, 0, stream>>>(xc, WvT, bvc, Vb, CD, CD, 1);

  attn<<<dim3(T_SZ / 64, B_SZ * NH), tb, 0, stream>>>(Qb, Kb, Vb, Yb);

  gemm_bt<<<gg, tb, 0, stream>>>(Yb, WoT, boc, Outc, CD, CD, 2);

  writeout<<<4096, tb, 0, stream>>>(Outc, flag, d_out, MROWS * CD / 8);
}

// Round 4
// 489.899 us; speedup vs baseline: 1.2122x; 1.2122x over previous
//
#include <hip/hip_runtime.h>
#include <cstdint>
#include <cstddef>

#define B_SZ 4
#define T_SZ 2048
#define NH 16
#define HD 64
#define CD 1024
#define MROWS (B_SZ*T_SZ)
#define NEG_BIG (-1e30f)
// 0.125 (1/sqrt(64)) * log2(e): fold softmax base-2 conversion into Q prescale
#define Q_SCALE 0.180336880f

typedef __bf16 bf16x8 __attribute__((ext_vector_type(8)));
typedef float f32x4 __attribute__((ext_vector_type(4)));
typedef unsigned short u16;

typedef __attribute__((address_space(3))) void* as3p;
typedef const __attribute__((address_space(1))) void* as1p;

__device__ __forceinline__ void glds16(const void* g, void* l) {
  __builtin_amdgcn_global_load_lds((as1p)g, (as3p)l, 16, 0, 0);
}

// ---------------------------------------------------------------------------
// Dtype discriminator (fp32 vs bf16 input encoding). flag=1 -> bf16.
// ---------------------------------------------------------------------------
__global__ __launch_bounds__(256) void detect_dtype(const uint32_t* __restrict__ x,
                                                    int* __restrict__ flag) {
  __shared__ int cnt[256];
  const int t = threadIdx.x;
  int c = 0;
  for (int i = 0; i < 4; i++) {
    uint32_t w = x[t * 4 + i];
    uint32_t e = (w >> 7) & 0xFF;
    c += (e >= 100 && e <= 140) ? 1 : 0;
  }
  cnt[t] = c;
  __syncthreads();
  for (int s = 128; s > 0; s >>= 1) {
    if (t < s) cnt[t] += cnt[t + s];
    __syncthreads();
  }
  if (t == 0) flag[0] = (cnt[0] > 700) ? 1 : 0;
}

__global__ __launch_bounds__(256) void conv_in(const void* __restrict__ src,
                                               const int* __restrict__ flag,
                                               __bf16* __restrict__ dst, int n8) {
  int i = blockIdx.x * 256 + threadIdx.x;
  if (i >= n8) return;
  bf16x8 o;
  if (flag[0]) {
    o = ((const bf16x8*)src)[i];
  } else {
    const float4* s = (const float4*)((const float*)src + (size_t)i * 8);
    float4 a = s[0], b = s[1];
    o[0] = (__bf16)a.x; o[1] = (__bf16)a.y; o[2] = (__bf16)a.z; o[3] = (__bf16)a.w;
    o[4] = (__bf16)b.x; o[5] = (__bf16)b.y; o[6] = (__bf16)b.z; o[7] = (__bf16)b.w;
  }
  ((bf16x8*)dst)[i] = o;
}

__global__ __launch_bounds__(256) void writeout(const __bf16* __restrict__ src,
                                                const int* __restrict__ flag,
                                                void* __restrict__ dst, int n8) {
  int i = blockIdx.x * 256 + threadIdx.x;
  if (i >= n8) return;
  bf16x8 v = ((const bf16x8*)src)[i];
  if (flag[0]) {
    ((bf16x8*)dst)[i] = v;
  } else {
    float4* d = (float4*)((float*)dst + (size_t)i * 8);
    float4 a, b;
    a.x = (float)v[0]; a.y = (float)v[1]; a.z = (float)v[2]; a.w = (float)v[3];
    b.x = (float)v[4]; b.y = (float)v[5]; b.z = (float)v[6]; b.w = (float)v[7];
    d[0] = a; d[1] = b;
  }
}

__global__ __launch_bounds__(256) void transpose_conv(const void* __restrict__ W,
                                                      const int* __restrict__ flag,
                                                      __bf16* __restrict__ WT) {
  __shared__ __align__(16) __bf16 tile[64 * 72];
  const int t = threadIdx.x;
  const int r0 = blockIdx.y * 64, c0 = blockIdx.x * 64;
  const int rr = t >> 3, c8 = (t & 7) * 8;
  const int isbf = flag[0];
  for (int p = 0; p < 2; p++) {
    int r = p * 32 + rr;
    bf16x8 v;
    if (isbf) {
      v = *(const bf16x8*)((const __bf16*)W + (size_t)(r0 + r) * CD + c0 + c8);
    } else {
      const float4* s = (const float4*)((const float*)W + (size_t)(r0 + r) * CD + c0 + c8);
      float4 a = s[0], b = s[1];
      v[0] = (__bf16)a.x; v[1] = (__bf16)a.y; v[2] = (__bf16)a.z; v[3] = (__bf16)a.w;
      v[4] = (__bf16)b.x; v[5] = (__bf16)b.y; v[6] = (__bf16)b.z; v[7] = (__bf16)b.w;
    }
    *(bf16x8*)(tile + r * 72 + c8) = v;
  }
  __syncthreads();
  for (int p = 0; p < 2; p++) {
    int cc = p * 32 + rr;
    bf16x8 o;
    for (int j = 0; j < 8; j++) o[j] = tile[(c8 + j) * 72 + cc];
    *(bf16x8*)(WT + (size_t)(c0 + cc) * CD + r0 + c8) = o;
  }
}

// ---------------------------------------------------------------------------
// V [bh][T][64] -> Vt [bh][64][T]  (tiled, vectorized both sides)
// ---------------------------------------------------------------------------
__global__ __launch_bounds__(256) void transpose_v(const __bf16* __restrict__ V,
                                                   __bf16* __restrict__ Vt) {
  __shared__ __align__(16) __bf16 tile[64 * 72];
  const int t = threadIdx.x;
  const int bh = blockIdx.y;
  const int k0 = blockIdx.x * 64;
  const int rr = t >> 3, c8 = (t & 7) * 8;
  const __bf16* Vb = V + (size_t)bh * T_SZ * HD;
  __bf16* Vo = Vt + (size_t)bh * HD * T_SZ;
  for (int p = 0; p < 2; p++) {
    int r = p * 32 + rr;
    *(bf16x8*)(tile + r * 72 + c8) = *(const bf16x8*)(Vb + (size_t)(k0 + r) * HD + c8);
  }
  __syncthreads();
  for (int p = 0; p < 2; p++) {
    int d = p * 32 + rr;
    bf16x8 o;
    for (int j = 0; j < 8; j++) o[j] = tile[(c8 + j) * 72 + d];
    *(bf16x8*)(Vo + (size_t)d * T_SZ + k0 + c8) = o;
  }
}

// ---------------------------------------------------------------------------
// C[M,N] = A[M,K] @ BT[N,K]^T + bias, canonical bf16, fp32 accum.
// mode 0: scale Q_SCALE, write [B,H,T,64]; mode 1: [B,H,T,64]; mode 2: flat.
// ---------------------------------------------------------------------------
__global__ __launch_bounds__(256) void gemm_bt(
    const __bf16* __restrict__ A, const __bf16* __restrict__ BT,
    const __bf16* __restrict__ bias, __bf16* __restrict__ Cout,
    int Kdim, int Ndim, int mode) {
  __shared__ __align__(16) __bf16 As[128 * 64];
  __shared__ __align__(16) __bf16 Bs[128 * 64];
  const int tid = threadIdx.x;
  const int w = tid >> 6, lane = tid & 63;
  const int l15 = lane & 15, quad = lane >> 4;
  const int wm = w & 1, wn = w >> 1;
  const int bm = blockIdx.y, bn = blockIdx.x;

  f32x4 acc[4][4];
  for (int i = 0; i < 4; i++)
    for (int j = 0; j < 4; j++) acc[i][j] = (f32x4)0.f;

  const int srow = lane >> 3, scol = (lane & 7) * 8;
  const __bf16* Abase = A + (size_t)(bm * 128) * Kdim;
  const __bf16* Bbase = BT + (size_t)(bn * 128) * Kdim;

  for (int k0 = 0; k0 < Kdim; k0 += 64) {
    __syncthreads();
    for (int p = 0; p < 4; p++) {
      int seg = p * 4 + w;
      int row = seg * 8 + srow;
      glds16(Abase + (size_t)row * Kdim + k0 + scol, (char*)As + seg * 1024);
      glds16(Bbase + (size_t)row * Kdim + k0 + scol, (char*)Bs + seg * 1024);
    }
    __syncthreads();
    for (int kc = 0; kc < 2; kc++) {
      const int koff = kc * 32 + quad * 8;
      bf16x8 af[4], bfr[4];
      for (int mt = 0; mt < 4; mt++)
        af[mt] = *(const bf16x8*)(As + (wm * 64 + mt * 16 + l15) * 64 + koff);
      for (int nt = 0; nt < 4; nt++)
        bfr[nt] = *(const bf16x8*)(Bs + (wn * 64 + nt * 16 + l15) * 64 + koff);
      for (int mt = 0; mt < 4; mt++)
        for (int nt = 0; nt < 4; nt++)
          acc[mt][nt] = __builtin_amdgcn_mfma_f32_16x16x32_bf16(
              af[mt], bfr[nt], acc[mt][nt], 0, 0, 0);
    }
  }

  for (int nt = 0; nt < 4; nt++) {
    int col = bn * 128 + wn * 64 + nt * 16 + l15;
    float bv = (float)bias[col];
    for (int mt = 0; mt < 4; mt++) {
      for (int r = 0; r < 4; r++) {
        int row = bm * 128 + wm * 64 + mt * 16 + quad * 4 + r;
        float v = acc[mt][nt][r] + bv;
        size_t idx;
        if (mode == 2) {
          idx = (size_t)row * Ndim + col;
        } else {
          if (mode == 0) v *= Q_SCALE;
          idx = (((size_t)(row >> 11) * NH + (col >> 6)) * T_SZ + (row & 2047)) * HD + (col & 63);
        }
        Cout[idx] = (__bf16)v;
      }
    }
  }
}

// ---------------------------------------------------------------------------
// Flash attention, causal. Q pre-scaled by 0.125*log2e (softmax in base 2).
// Q/K: [B*H, T, 64]; Vt: [B*H, 64, T]. Q-tile 128 (4 waves x 32 q-rows),
// KV-tile 64. Y: [B*T, 1024].
// ---------------------------------------------------------------------------
__global__ __launch_bounds__(256, 4) void attn(
    const __bf16* __restrict__ Q, const __bf16* __restrict__ K,
    const __bf16* __restrict__ Vt, __bf16* __restrict__ Y) {
  __shared__ __align__(16) __bf16 Ks[64 * 72];
  __shared__ __align__(16) __bf16 Vs[64 * 72];      // [d][key]
  __shared__ __align__(16) __bf16 Ps[4][32 * 72];

  const int tid = threadIdx.x, w = tid >> 6, lane = tid & 63;
  const int l15 = lane & 15, quad = lane >> 4;
  const int bh = blockIdx.y;
  const int q0 = blockIdx.x * 128;

  const __bf16* Qbh = Q + (size_t)bh * T_SZ * HD;
  const __bf16* Kbh = K + (size_t)bh * T_SZ * HD;
  const __bf16* Vbh = Vt + (size_t)bh * HD * T_SZ;

  bf16x8 aq[2][2];
  for (int mt = 0; mt < 2; mt++)
    for (int kc = 0; kc < 2; kc++)
      aq[mt][kc] = *(const bf16x8*)(
          Qbh + (size_t)(q0 + w * 32 + mt * 16 + l15) * HD + kc * 32 + quad * 8);

  f32x4 acco[2][4];
  for (int mt = 0; mt < 2; mt++)
    for (int dt = 0; dt < 4; dt++) acco[mt][dt] = (f32x4)0.f;
  float m_[2][4], l_[2][4];
  for (int mt = 0; mt < 2; mt++)
    for (int r = 0; r < 4; r++) { m_[mt][r] = NEG_BIG; l_[mt][r] = 0.f; }

  const int srow = tid >> 2;          // 0..63
  const int scol = (tid & 3) * 8;     // 0,8,16,24

  for (int kv0 = 0; kv0 < q0 + 128; kv0 += 64) {
    __syncthreads();
    for (int p = 0; p < 2; p++) {
      int c = scol + p * 32;
      *(bf16x8*)(Ks + srow * 72 + c) =
          *(const bf16x8*)(Kbh + (size_t)(kv0 + srow) * HD + c);
      *(bf16x8*)(Vs + srow * 72 + c) =
          *(const bf16x8*)(Vbh + (size_t)srow * T_SZ + kv0 + c);
    }
    __syncthreads();

    // S = Q K^T : 32 q-rows x 64 keys per wave
    f32x4 accs[2][4];
    for (int mt = 0; mt < 2; mt++)
      for (int nt = 0; nt < 4; nt++) accs[mt][nt] = (f32x4)0.f;
    for (int kc = 0; kc < 2; kc++)
      for (int nt = 0; nt < 4; nt++) {
        bf16x8 bk = *(const bf16x8*)(Ks + (nt * 16 + l15) * 72 + kc * 32 + quad * 8);
        for (int mt = 0; mt < 2; mt++)
          accs[mt][nt] = __builtin_amdgcn_mfma_f32_16x16x32_bf16(
              aq[mt][kc], bk, accs[mt][nt], 0, 0, 0);
      }

    // causal mask (only the last two KV tiles can cross the diagonal)
    if (kv0 + 63 >= q0) {
      for (int mt = 0; mt < 2; mt++)
        for (int nt = 0; nt < 4; nt++) {
          int kg = kv0 + nt * 16 + l15;
          int qb = q0 + w * 32 + mt * 16 + quad * 4;
          for (int r = 0; r < 4; r++)
            if (kg > qb + r) accs[mt][nt][r] = NEG_BIG;
        }
    }

    // online softmax (base-2)
    float mloc[2][4];
    for (int mt = 0; mt < 2; mt++)
      for (int r = 0; r < 4; r++) {
        float m0 = fmaxf(accs[mt][0][r], accs[mt][1][r]);
        float m1 = fmaxf(accs[mt][2][r], accs[mt][3][r]);
        mloc[mt][r] = fmaxf(m0, m1);
      }
    for (int off = 1; off < 16; off <<= 1)
      for (int mt = 0; mt < 2; mt++)
        for (int r = 0; r < 4; r++)
          mloc[mt][r] = fmaxf(mloc[mt][r], __shfl_xor(mloc[mt][r], off));

    float alpha[2][4], rs[2][4];
    for (int mt = 0; mt < 2; mt++)
      for (int r = 0; r < 4; r++) {
        float mnew = fmaxf(m_[mt][r], mloc[mt][r]);
        alpha[mt][r] = exp2f(m_[mt][r] - mnew);
        m_[mt][r] = mnew;
        rs[mt][r] = 0.f;
      }
    for (int mt = 0; mt < 2; mt++)
      for (int nt = 0; nt < 4; nt++)
        for (int r = 0; r < 4; r++) {
          float p = exp2f(accs[mt][nt][r] - m_[mt][r]);
          rs[mt][r] += p;
          Ps[w][(mt * 16 + quad * 4 + r) * 72 + nt * 16 + l15] = (__bf16)p;
        }
    for (int off = 1; off < 16; off <<= 1)
      for (int mt = 0; mt < 2; mt++)
        for (int r = 0; r < 4; r++) rs[mt][r] += __shfl_xor(rs[mt][r], off);
    for (int mt = 0; mt < 2; mt++)
      for (int r = 0; r < 4; r++) l_[mt][r] = l_[mt][r] * alpha[mt][r] + rs[mt][r];
    for (int mt = 0; mt < 2; mt++)
      for (int dt = 0; dt < 4; dt++)
        for (int r = 0; r < 4; r++) acco[mt][dt][r] *= alpha[mt][r];

    // per-wave P round-trip: drain LDS writes, pin ordering (no block barrier)
    __builtin_amdgcn_fence(__ATOMIC_ACQ_REL, "workgroup");

    // O += P V
    for (int kc = 0; kc < 2; kc++) {
      bf16x8 ap[2];
      for (int mt = 0; mt < 2; mt++)
        ap[mt] = *(const bf16x8*)(Ps[w] + (mt * 16 + l15) * 72 + kc * 32 + quad * 8);
      for (int dt = 0; dt < 4; dt++) {
        bf16x8 bv = *(const bf16x8*)(Vs + (dt * 16 + l15) * 72 + kc * 32 + quad * 8);
        for (int mt = 0; mt < 2; mt++)
          acco[mt][dt] = __builtin_amdgcn_mfma_f32_16x16x32_bf16(
              ap[mt], bv, acco[mt][dt], 0, 0, 0);
      }
    }
  }

  const int b = bh >> 4, h = bh & 15;
  for (int mt = 0; mt < 2; mt++)
    for (int r = 0; r < 4; r++) {
      float rcp = 1.f / l_[mt][r];
      int qg = q0 + w * 32 + mt * 16 + quad * 4 + r;
      for (int dt = 0; dt < 4; dt++)
        Y[((size_t)(b * T_SZ + qg)) * CD + h * HD + dt * 16 + l15] =
            (__bf16)(acco[mt][dt][r] * rcp);
    }
}

// ---------------------------------------------------------------------------
extern "C" void kernel_launch(void* const* d_in, const int* in_sizes, int n_in,
                              void* d_out, int out_size, void* d_ws, size_t ws_size,
                              hipStream_t stream) {
  (void)in_sizes; (void)n_in; (void)out_size; (void)ws_size;
  const void* x  = d_in[0];
  const void* Wq = d_in[2];
  const void* bq = d_in[3];
  const void* Wk = d_in[4];
  const void* bk = d_in[5];
  const void* Wv = d_in[6];
  const void* bv = d_in[7];
  const void* Wo = d_in[8];
  const void* bo = d_in[9];

  char* ws = (char*)d_ws;
  const size_t MB = 1024 * 1024;
  __bf16* WqT  = (__bf16*)(ws + 0 * MB);
  __bf16* WkT  = (__bf16*)(ws + 2 * MB);
  __bf16* WvT  = (__bf16*)(ws + 4 * MB);
  __bf16* WoT  = (__bf16*)(ws + 6 * MB);
  __bf16* bqc  = (__bf16*)(ws + 8 * MB);
  __bf16* bkc  = (__bf16*)(ws + 8 * MB + 8192);
  __bf16* bvc  = (__bf16*)(ws + 8 * MB + 16384);
  __bf16* boc  = (__bf16*)(ws + 8 * MB + 24576);
  int*    flag = (int*)   (ws + 8 * MB + 65536);
  __bf16* xc   = (__bf16*)(ws + 9 * MB);    // [8192,1024]; reused as Vt_g
  __bf16* Qb   = (__bf16*)(ws + 25 * MB);   // [B*H,T,64] pre-scaled
  __bf16* Kb   = (__bf16*)(ws + 41 * MB);   // reused as Outc
  __bf16* Vb   = (__bf16*)(ws + 57 * MB);   // reused as Yb
  __bf16* Vt_g = xc;                        // xc dead after V-GEMM
  __bf16* Yb   = Vb;                        // Vb dead after transpose_v
  __bf16* Outc = Kb;                        // Kb dead after attn

  dim3 tb(256);
  detect_dtype<<<1, tb, 0, stream>>>((const uint32_t*)x, flag);

  conv_in<<<4096, tb, 0, stream>>>(x, flag, xc, MROWS * CD / 8);
  conv_in<<<1, tb, 0, stream>>>(bq, flag, bqc, CD / 8);
  conv_in<<<1, tb, 0, stream>>>(bk, flag, bkc, CD / 8);
  conv_in<<<1, tb, 0, stream>>>(bv, flag, bvc, CD / 8);
  conv_in<<<1, tb, 0, stream>>>(bo, flag, boc, CD / 8);

  dim3 tg(16, 16);
  transpose_conv<<<tg, tb, 0, stream>>>(Wq, flag, WqT);
  transpose_conv<<<tg, tb, 0, stream>>>(Wk, flag, WkT);
  transpose_conv<<<tg, tb, 0, stream>>>(Wv, flag, WvT);
  transpose_conv<<<tg, tb, 0, stream>>>(Wo, flag, WoT);

  dim3 gg(CD / 128, MROWS / 128);
  gemm_bt<<<gg, tb, 0, stream>>>(xc, WqT, bqc, Qb, CD, CD, 0);
  gemm_bt<<<gg, tb, 0, stream>>>(xc, WkT, bkc, Kb, CD, CD, 1);
  gemm_bt<<<gg, tb, 0, stream>>>(xc, WvT, bvc, Vb, CD, CD, 1);

  transpose_v<<<dim3(T_SZ / 64, B_SZ * NH), tb, 0, stream>>>(Vb, Vt_g);

  attn<<<dim3(T_SZ / 128, B_SZ * NH), tb, 0, stream>>>(Qb, Kb, Vt_g, Yb);

  gemm_bt<<<gg, tb, 0, stream>>>(Yb, WoT, boc, Outc, CD, CD, 2);

  writeout<<<4096, tb, 0, stream>>>(Outc, flag, d_out, MROWS * CD / 8);
}

// Round 5
// 361.811 us; speedup vs baseline: 1.6413x; 1.3540x over previous
//
#include <hip/hip_runtime.h>
#include <cstdint>
#include <cstddef>

#define B_SZ 4
#define T_SZ 2048
#define NH 16
#define HD 64
#define CD 1024
#define MROWS (B_SZ*T_SZ)
#define NEG_BIG (-1e30f)
// 0.125 (1/sqrt(64)) * log2(e): fold softmax base-2 conversion into Q prescale
#define Q_SCALE 0.180336880f

typedef __bf16 bf16x8 __attribute__((ext_vector_type(8)));
typedef __bf16 bf16x4 __attribute__((ext_vector_type(4)));
typedef short s16x4 __attribute__((ext_vector_type(4)));
typedef float f32x4 __attribute__((ext_vector_type(4)));

typedef __attribute__((address_space(3))) void* as3p;
typedef const __attribute__((address_space(1))) void* as1p;

__device__ __forceinline__ void glds16(const void* g, void* l) {
  __builtin_amdgcn_global_load_lds((as1p)g, (as3p)l, 16, 0, 0);
}

// ---------------------------------------------------------------------------
// Dtype discriminator (fp32 vs bf16 input encoding). flag=1 -> bf16.
// ---------------------------------------------------------------------------
__global__ __launch_bounds__(256) void detect_dtype(const uint32_t* __restrict__ x,
                                                    int* __restrict__ flag) {
  __shared__ int cnt[256];
  const int t = threadIdx.x;
  int c = 0;
  for (int i = 0; i < 4; i++) {
    uint32_t w = x[t * 4 + i];
    uint32_t e = (w >> 7) & 0xFF;
    c += (e >= 100 && e <= 140) ? 1 : 0;
  }
  cnt[t] = c;
  __syncthreads();
  for (int s = 128; s > 0; s >>= 1) {
    if (t < s) cnt[t] += cnt[t + s];
    __syncthreads();
  }
  if (t == 0) flag[0] = (cnt[0] > 700) ? 1 : 0;
}

__device__ __forceinline__ bf16x8 cvt8(const void* src, int isbf, size_t i8) {
  bf16x8 o;
  if (isbf) {
    o = ((const bf16x8*)src)[i8];
  } else {
    const float4* s = (const float4*)((const float*)src + i8 * 8);
    float4 a = s[0], b = s[1];
    o[0] = (__bf16)a.x; o[1] = (__bf16)a.y; o[2] = (__bf16)a.z; o[3] = (__bf16)a.w;
    o[4] = (__bf16)b.x; o[5] = (__bf16)b.y; o[6] = (__bf16)b.z; o[7] = (__bf16)b.w;
  }
  return o;
}

__global__ __launch_bounds__(256) void conv_in(const void* __restrict__ src,
                                               const int* __restrict__ flag,
                                               __bf16* __restrict__ dst, int n8) {
  int i = blockIdx.x * 256 + threadIdx.x;
  if (i >= n8) return;
  ((bf16x8*)dst)[i] = cvt8(src, flag[0], i);
}

struct Ptr4 { const void* s[4]; __bf16* d[4]; };

__global__ __launch_bounds__(256) void conv_b4(Ptr4 p, const int* __restrict__ flag) {
  int i = threadIdx.x;
  if (i >= CD / 8) return;
  int which = blockIdx.x;
  ((bf16x8*)p.d[which])[i] = cvt8(p.s[which], flag[0], i);
}

__global__ __launch_bounds__(256) void writeout(const __bf16* __restrict__ src,
                                                const int* __restrict__ flag,
                                                void* __restrict__ dst, int n8) {
  int i = blockIdx.x * 256 + threadIdx.x;
  if (i >= n8) return;
  bf16x8 v = ((const bf16x8*)src)[i];
  if (flag[0]) {
    ((bf16x8*)dst)[i] = v;
  } else {
    float4* d = (float4*)((float*)dst + (size_t)i * 8);
    float4 a, b;
    a.x = (float)v[0]; a.y = (float)v[1]; a.z = (float)v[2]; a.w = (float)v[3];
    b.x = (float)v[4]; b.y = (float)v[5]; b.z = (float)v[6]; b.w = (float)v[7];
    d[0] = a; d[1] = b;
  }
}

// 4 weight matrices 1024x1024 -> transposed canonical bf16 (z selects)
__global__ __launch_bounds__(256) void transpose_conv4(Ptr4 p,
                                                       const int* __restrict__ flag) {
  __shared__ __align__(16) __bf16 tile[64 * 72];
  const void* W = p.s[blockIdx.z];
  __bf16* WT = p.d[blockIdx.z];
  const int t = threadIdx.x;
  const int r0 = blockIdx.y * 64, c0 = blockIdx.x * 64;
  const int rr = t >> 3, c8 = (t & 7) * 8;
  const int isbf = flag[0];
  for (int pp = 0; pp < 2; pp++) {
    int r = pp * 32 + rr;
    *(bf16x8*)(tile + r * 72 + c8) =
        cvt8(W, isbf, ((size_t)(r0 + r) * CD + c0 + c8) / 8);
  }
  __syncthreads();
  for (int pp = 0; pp < 2; pp++) {
    int cc = pp * 32 + rr;
    bf16x8 o;
    for (int j = 0; j < 8; j++) o[j] = tile[(c8 + j) * 72 + cc];
    *(bf16x8*)(WT + (size_t)(c0 + cc) * CD + r0 + c8) = o;
  }
}

// ---------------------------------------------------------------------------
// C[M,N] = A[M,K] @ BT[N,K]^T + bias, canonical bf16, fp32 accum.
// mode 0: scale Q_SCALE, write [B,H,T,64]; mode 1: [B,H,T,64];
// mode 2: flat [M,N]; mode 3: V transposed -> [B*H, 64, T].
// ---------------------------------------------------------------------------
__global__ __launch_bounds__(256) void gemm_bt(
    const __bf16* __restrict__ A, const __bf16* __restrict__ BT,
    const __bf16* __restrict__ bias, __bf16* __restrict__ Cout,
    int Kdim, int Ndim, int mode) {
  __shared__ __align__(16) __bf16 As[128 * 64];
  __shared__ __align__(16) __bf16 Bs[128 * 64];
  const int tid = threadIdx.x;
  const int w = tid >> 6, lane = tid & 63;
  const int l15 = lane & 15, quad = lane >> 4;
  const int wm = w & 1, wn = w >> 1;
  const int bm = blockIdx.y, bn = blockIdx.x;

  f32x4 acc[4][4];
  for (int i = 0; i < 4; i++)
    for (int j = 0; j < 4; j++) acc[i][j] = (f32x4)0.f;

  const int srow = lane >> 3, scol = (lane & 7) * 8;
  const __bf16* Abase = A + (size_t)(bm * 128) * Kdim;
  const __bf16* Bbase = BT + (size_t)(bn * 128) * Kdim;

  for (int k0 = 0; k0 < Kdim; k0 += 64) {
    __syncthreads();
    for (int p = 0; p < 4; p++) {
      int seg = p * 4 + w;
      int row = seg * 8 + srow;
      glds16(Abase + (size_t)row * Kdim + k0 + scol, (char*)As + seg * 1024);
      glds16(Bbase + (size_t)row * Kdim + k0 + scol, (char*)Bs + seg * 1024);
    }
    __syncthreads();
    for (int kc = 0; kc < 2; kc++) {
      const int koff = kc * 32 + quad * 8;
      bf16x8 af[4], bfr[4];
      for (int mt = 0; mt < 4; mt++)
        af[mt] = *(const bf16x8*)(As + (wm * 64 + mt * 16 + l15) * 64 + koff);
      for (int nt = 0; nt < 4; nt++)
        bfr[nt] = *(const bf16x8*)(Bs + (wn * 64 + nt * 16 + l15) * 64 + koff);
      for (int mt = 0; mt < 4; mt++)
        for (int nt = 0; nt < 4; nt++)
          acc[mt][nt] = __builtin_amdgcn_mfma_f32_16x16x32_bf16(
              af[mt], bfr[nt], acc[mt][nt], 0, 0, 0);
    }
  }

  for (int nt = 0; nt < 4; nt++) {
    int col = bn * 128 + wn * 64 + nt * 16 + l15;
    float bv = (float)bias[col];
    for (int mt = 0; mt < 4; mt++) {
      if (mode == 3) {
        // rows: bm*128+wm*64+mt*16+quad*4 + r -> 4 consecutive tokens
        int row0 = bm * 128 + wm * 64 + mt * 16 + quad * 4;
        int b = row0 >> 11, tok = row0 & 2047;
        bf16x4 o;
        for (int r = 0; r < 4; r++) o[r] = (__bf16)(acc[mt][nt][r] + bv);
        size_t idx = ((size_t)((b << 4) + (col >> 6)) * HD + (col & 63)) * T_SZ + tok;
        *(bf16x4*)(Cout + idx) = o;
      } else {
        for (int r = 0; r < 4; r++) {
          int row = bm * 128 + wm * 64 + mt * 16 + quad * 4 + r;
          float v = acc[mt][nt][r] + bv;
          size_t idx;
          if (mode == 2) {
            idx = (size_t)row * Ndim + col;
          } else {
            if (mode == 0) v *= Q_SCALE;
            idx = (((size_t)(row >> 11) * NH + (col >> 6)) * T_SZ + (row & 2047)) * HD + (col & 63);
          }
          Cout[idx] = (__bf16)v;
        }
      }
    }
  }
}

// ---------------------------------------------------------------------------
// Flash attention, causal, transposed-S formulation.
// Q pre-scaled by 0.125*log2e. Q/K: [B*H, T, 64]; Vt: [B*H, 64, T].
// Block = pair of Q-tiles {i, 15-i} (128 q each) -> 34 KV-iters per block
// (perfect balance). Per wave: 32 q-rows. S^T = K Q^T; P^T stays in regs
// (C layout == x16 B-operand layout); O^T = V^T P^T via mfma 16x16x16.
// Double-buffered K/V LDS, one barrier per iter.
// ---------------------------------------------------------------------------
__global__ __launch_bounds__(256) void attn(
    const __bf16* __restrict__ Q, const __bf16* __restrict__ K,
    const __bf16* __restrict__ Vt, __bf16* __restrict__ Y) {
  __shared__ __align__(16) __bf16 Ks[2][64 * 72];
  __shared__ __align__(16) __bf16 Vs[2][64 * 72];   // [d][key]

  const int tid = threadIdx.x, w = tid >> 6, lane = tid & 63;
  const int l15 = lane & 15, quad = lane >> 4;
  const int bh = blockIdx.y;
  const int pairi = blockIdx.x;                      // 0..7

  const __bf16* Qbh = Q + (size_t)bh * T_SZ * HD;
  const __bf16* Kbh = K + (size_t)bh * T_SZ * HD;
  const __bf16* Vbh = Vt + (size_t)bh * HD * T_SZ;

  const int srow = tid >> 2;          // 0..63
  const int scol = (tid & 3) * 8;     // 0,8,16,24
  const int b = bh >> 4, h = bh & 15;

  for (int ph = 0; ph < 2; ph++) {
    const int tq = ph ? (15 - pairi) : pairi;
    const int q0 = tq * 128;
    const int niter = (q0 >> 6) + 2;

    __syncthreads();   // prior phase done with LDS
    // prologue: stage KV tile 0 into buffer 0
    for (int p = 0; p < 2; p++) {
      int c = scol + p * 32;
      *(bf16x8*)(Ks[0] + srow * 72 + c) = *(const bf16x8*)(Kbh + (size_t)srow * HD + c);
      *(bf16x8*)(Vs[0] + srow * 72 + c) = *(const bf16x8*)(Vbh + (size_t)srow * T_SZ + c);
    }

    // Q fragments (B-operand: n=l15->q, k=quad*8+j->d)
    bf16x8 aq[2][2];
    for (int mt = 0; mt < 2; mt++)
      for (int kc = 0; kc < 2; kc++)
        aq[mt][kc] = *(const bf16x8*)(
            Qbh + (size_t)(q0 + w * 32 + mt * 16 + l15) * HD + kc * 32 + quad * 8);

    f32x4 acco[2][4];     // O^T tiles [d16 x q16]: row d=quad*4+r, col q=l15
    for (int mt = 0; mt < 2; mt++)
      for (int dt = 0; dt < 4; dt++) acco[mt][dt] = (f32x4)0.f;
    float m_[2], l_[2];
    for (int mt = 0; mt < 2; mt++) { m_[mt] = NEG_BIG; l_[mt] = 0.f; }

    for (int it = 0; it < niter; it++) {
      const int cur = it & 1;
      const int kv0 = it * 64;
      __syncthreads();

      // prefetch next KV tile into regs (overlaps compute)
      bf16x8 kn[2], vn[2];
      const bool havenext = (it + 1 < niter);
      if (havenext) {
        int kv1 = kv0 + 64;
        for (int p = 0; p < 2; p++) {
          int c = scol + p * 32;
          kn[p] = *(const bf16x8*)(Kbh + (size_t)(kv1 + srow) * HD + c);
          vn[p] = *(const bf16x8*)(Vbh + (size_t)srow * T_SZ + kv1 + c);
        }
      }

      const __bf16* Ksc = Ks[cur];
      const __bf16* Vsc = Vs[cur];

      // S^T = K Q^T : tiles [key16 x q16]; row key=quad*4+r, col q=l15
      f32x4 accs[2][4];
      for (int mt = 0; mt < 2; mt++)
        for (int nt = 0; nt < 4; nt++) accs[mt][nt] = (f32x4)0.f;
      for (int kc = 0; kc < 2; kc++)
        for (int nt = 0; nt < 4; nt++) {
          bf16x8 ak = *(const bf16x8*)(Ksc + (nt * 16 + l15) * 72 + kc * 32 + quad * 8);
          for (int mt = 0; mt < 2; mt++)
            accs[mt][nt] = __builtin_amdgcn_mfma_f32_16x16x32_bf16(
                ak, aq[mt][kc], accs[mt][nt], 0, 0, 0);
        }

      // causal mask
      for (int mt = 0; mt < 2; mt++) {
        int qg = q0 + w * 32 + mt * 16 + l15;
        if (kv0 + 63 > q0 + w * 32 + mt * 16) {
          for (int nt = 0; nt < 4; nt++) {
            int kg0 = kv0 + nt * 16 + quad * 4;
            for (int r = 0; r < 4; r++)
              if (kg0 + r > qg) accs[mt][nt][r] = NEG_BIG;
          }
        }
      }

      // online softmax over keys (rows + cross-quad)
      float mloc[2], alpha[2], rs[2];
      for (int mt = 0; mt < 2; mt++) {
        float a0 = fmaxf(fmaxf(accs[mt][0][0], accs[mt][0][1]),
                         fmaxf(accs[mt][0][2], accs[mt][0][3]));
        float a1 = fmaxf(fmaxf(accs[mt][1][0], accs[mt][1][1]),
                         fmaxf(accs[mt][1][2], accs[mt][1][3]));
        float a2 = fmaxf(fmaxf(accs[mt][2][0], accs[mt][2][1]),
                         fmaxf(accs[mt][2][2], accs[mt][2][3]));
        float a3 = fmaxf(fmaxf(accs[mt][3][0], accs[mt][3][1]),
                         fmaxf(accs[mt][3][2], accs[mt][3][3]));
        mloc[mt] = fmaxf(fmaxf(a0, a1), fmaxf(a2, a3));
      }
      for (int off = 16; off < 64; off <<= 1)
        for (int mt = 0; mt < 2; mt++)
          mloc[mt] = fmaxf(mloc[mt], __shfl_xor(mloc[mt], off));
      for (int mt = 0; mt < 2; mt++) {
        float mnew = fmaxf(m_[mt], mloc[mt]);
        alpha[mt] = exp2f(m_[mt] - mnew);
        m_[mt] = mnew;
        rs[mt] = 0.f;
      }

      // P^T = exp2(S^T - m): stays in regs as x16 B-operand fragments
      bf16x4 pf[2][4];
      for (int mt = 0; mt < 2; mt++)
        for (int nt = 0; nt < 4; nt++) {
          for (int r = 0; r < 4; r++) {
            float p = exp2f(accs[mt][nt][r] - m_[mt]);
            rs[mt] += p;
            pf[mt][nt][r] = (__bf16)p;
          }
        }
      for (int off = 16; off < 64; off <<= 1)
        for (int mt = 0; mt < 2; mt++) rs[mt] += __shfl_xor(rs[mt], off);
      for (int mt = 0; mt < 2; mt++) l_[mt] = l_[mt] * alpha[mt] + rs[mt];
      for (int mt = 0; mt < 2; mt++)
        for (int dt = 0; dt < 4; dt++)
          for (int r = 0; r < 4; r++) acco[mt][dt][r] *= alpha[mt];

      // O^T += V^T P^T  (x16 MFMA; A from Vs, B from regs)
      for (int nt = 0; nt < 4; nt++)
        for (int dt = 0; dt < 4; dt++) {
          bf16x4 av = *(const bf16x4*)(Vsc + (dt * 16 + l15) * 72 + nt * 16 + quad * 4);
          for (int mt = 0; mt < 2; mt++)
            acco[mt][dt] = __builtin_amdgcn_mfma_f32_16x16x16bf16_1k(
                *(const s16x4*)&av, *(const s16x4*)&pf[mt][nt], acco[mt][dt], 0, 0, 0);
        }

      // stage prefetched tile into the other buffer
      if (havenext) {
        int nb = cur ^ 1;
        for (int p = 0; p < 2; p++) {
          int c = scol + p * 32;
          *(bf16x8*)(Ks[nb] + srow * 72 + c) = kn[p];
          *(bf16x8*)(Vs[nb] + srow * 72 + c) = vn[p];
        }
      }
    }

    // epilogue: O^T -> Y [B*T, 1024], 8B stores (4 consecutive d)
    for (int mt = 0; mt < 2; mt++) {
      float rcp = 1.f / l_[mt];
      int qg = q0 + w * 32 + mt * 16 + l15;
      size_t base = ((size_t)(b * T_SZ + qg)) * CD + h * HD + quad * 4;
      for (int dt = 0; dt < 4; dt++) {
        bf16x4 o;
        for (int r = 0; r < 4; r++) o[r] = (__bf16)(acco[mt][dt][r] * rcp);
        *(bf16x4*)(Y + base + dt * 16) = o;
      }
    }
  }
}

// ---------------------------------------------------------------------------
extern "C" void kernel_launch(void* const* d_in, const int* in_sizes, int n_in,
                              void* d_out, int out_size, void* d_ws, size_t ws_size,
                              hipStream_t stream) {
  (void)in_sizes; (void)n_in; (void)out_size; (void)ws_size;
  const void* x  = d_in[0];
  const void* Wq = d_in[2];
  const void* bq = d_in[3];
  const void* Wk = d_in[4];
  const void* bk = d_in[5];
  const void* Wv = d_in[6];
  const void* bv = d_in[7];
  const void* Wo = d_in[8];
  const void* bo = d_in[9];

  char* ws = (char*)d_ws;
  const size_t MB = 1024 * 1024;
  __bf16* WqT  = (__bf16*)(ws + 0 * MB);
  __bf16* WkT  = (__bf16*)(ws + 2 * MB);
  __bf16* WvT  = (__bf16*)(ws + 4 * MB);
  __bf16* WoT  = (__bf16*)(ws + 6 * MB);
  __bf16* bqc  = (__bf16*)(ws + 8 * MB);
  __bf16* bkc  = (__bf16*)(ws + 8 * MB + 8192);
  __bf16* bvc  = (__bf16*)(ws + 8 * MB + 16384);
  __bf16* boc  = (__bf16*)(ws + 8 * MB + 24576);
  int*    flag = (int*)   (ws + 8 * MB + 65536);
  __bf16* xc   = (__bf16*)(ws + 9 * MB);    // [8192,1024]; reused as Yb
  __bf16* Qb   = (__bf16*)(ws + 25 * MB);   // [B*H,T,64] pre-scaled
  __bf16* Kb   = (__bf16*)(ws + 41 * MB);   // reused as Outc
  __bf16* Vt_g = (__bf16*)(ws + 57 * MB);   // [B*H,64,T]
  __bf16* Yb   = xc;                        // xc dead after QKV GEMMs
  __bf16* Outc = Kb;                        // Kb dead after attn

  dim3 tb(256);
  detect_dtype<<<1, tb, 0, stream>>>((const uint32_t*)x, flag);

  conv_in<<<4096, tb, 0, stream>>>(x, flag, xc, MROWS * CD / 8);
  Ptr4 pb = {{bq, bk, bv, bo}, {bqc, bkc, bvc, boc}};
  conv_b4<<<4, tb, 0, stream>>>(pb, flag);
  Ptr4 pw = {{Wq, Wk, Wv, Wo}, {WqT, WkT, WvT, WoT}};
  transpose_conv4<<<dim3(16, 16, 4), tb, 0, stream>>>(pw, flag);

  dim3 gg(CD / 128, MROWS / 128);
  gemm_bt<<<gg, tb, 0, stream>>>(xc, WqT, bqc, Qb, CD, CD, 0);
  gemm_bt<<<gg, tb, 0, stream>>>(xc, WkT, bkc, Kb, CD, CD, 1);
  gemm_bt<<<gg, tb, 0, stream>>>(xc, WvT, bvc, Vt_g, CD, CD, 3);

  attn<<<dim3(8, B_SZ * NH), tb, 0, stream>>>(Qb, Kb, Vt_g, Yb);

  gemm_bt<<<gg, tb, 0, stream>>>(Yb, WoT, boc, Outc, CD, CD, 2);

  writeout<<<4096, tb, 0, stream>>>(Outc, flag, d_out, MROWS * CD / 8);
}